// Round 4
// baseline (532.296 us; speedup 1.0000x reference)
//
#include <hip/hip_runtime.h>
#include <hip/hip_bf16.h>

// Batched Kronecker product:
//   A: (8, 64, 64) fp32, B: (8, 64, 64) fp32
//   out[b, i*64+p, j*64+q] = A[b,i,j] * B[b,p,q]  -> (8, 4096, 4096) fp32
//
// Output = 512 MiB -> pure write-BW-bound. Inputs (128 KiB each) live in L1/L2.
// One float4 (16 B) store per thread-iteration; all dims are powers of two so
// index decode is shifts/masks. 64 % 4 == 0 so each float4 of output has a
// single A scalar and 4 contiguous B elements.

__global__ __launch_bounds__(256) void kron_f32_kernel(
    const float* __restrict__ A,
    const float* __restrict__ B,
    float* __restrict__ out,
    unsigned int n4)   // number of float4 output elements = total/4 (2^25, fits u32)
{
    unsigned int idx = blockIdx.x * blockDim.x + threadIdx.x;
    const unsigned int stride = gridDim.x * blockDim.x;
    #pragma unroll 2
    for (; idx < n4; idx += stride) {
        const unsigned int e = idx << 2;              // flat element index (< 2^27)
        const unsigned int b   = e >> 24;             // 4096*4096 = 2^24 per batch
        const unsigned int rem = e & 0xFFFFFFu;
        const unsigned int r = rem >> 12;             // output row (0..4095)
        const unsigned int c = rem & 4095u;           // output col (0..4095)
        const unsigned int i = r >> 6, p = r & 63u;
        const unsigned int j = c >> 6, q = c & 63u;   // q % 4 == 0

        const float a = A[(b << 12) + (i << 6) + j];
        const float4 bv = *reinterpret_cast<const float4*>(&B[(b << 12) + (p << 6) + q]);

        float4 o;
        o.x = a * bv.x;
        o.y = a * bv.y;
        o.z = a * bv.z;
        o.w = a * bv.w;
        *reinterpret_cast<float4*>(&out[e]) = o;
    }
}

extern "C" void kernel_launch(void* const* d_in, const int* in_sizes, int n_in,
                              void* d_out, int out_size, void* d_ws, size_t ws_size,
                              hipStream_t stream) {
    const float* A = (const float*)d_in[0];
    const float* B = (const float*)d_in[1];
    float* out = (float*)d_out;

    const unsigned int n4 = (unsigned int)(out_size / 4);   // 134,217,728 / 4 = 2^25
    const int block = 256;
    int grid = 2048;                                        // grid-stride; ~8 blocks/CU
    kron_f32_kernel<<<grid, block, 0, stream>>>(A, B, out, n4);
}